// Round 1
// 174.017 us; speedup vs baseline: 1.0119x; 1.0119x over previous
//
#include <hip/hip_runtime.h>
#include <hip/hip_bf16.h>
#include <stdint.h>

// GroupTorchGRU: B=1024, U=8, I=H=512, fp32 in/out.
// R9: K1 prepass (fp32->bf16) + K2 fused GEMM+gates with a 4-deep
// counted-vmcnt pipeline (T3/T4):
//  - 4 x 40KB circular LDS buffer (160KB, 1 block/CU). Prologue issues
//    tiles 0..2; per iter: s_waitcnt vmcnt(10) (retire ONLY this tile's
//    5 loads/wave, keep 2 tiles in flight ACROSS the barrier), raw
//    s_barrier, issue tile it+3, ds_read + MFMA under s_setprio(1).
//    R8's __syncthreads() drained vmcnt(0) every iter -> ~900cy uncovered
//    load latency x16 iters (MfmaUtil 12%). Counted waits remove it.
//  - vmcnt accounting is exact: 5 global_load_lds per wave per tile and
//    NO other vmem op can enter the K-loop (epilogue bias/hidden loads
//    cannot be hoisted above the in-loop "memory"-clobber asm).
//  - Overwrite safety: tile it+3 -> slot (it-1)&3, whose readers all
//    passed the barrier of iter it; wait-before-barrier publishes each
//    wave's own loads workgroup-wide.
//  - gate-split waves (0-3 gx / 4-7 gh), 64x32 wave tile, 32x32x16 MFMA,
//    XOR swizzle (verified conflict-free), XCD-aware grid (x%8 = nb).
// Fallback: proven R3 single-kernel path if ws too small.

#define B_ 1024
#define U_ 8
#define I_ 512
#define H_ 512
#define KDIM 512

#define NX (B_ * U_ * I_)
#define NW (U_ * 3 * H_ * I_)
#define OFF_X 0
#define OFF_H NX
#define OFF_WIH (2 * NX)
#define OFF_WHH (2 * NX + NW)
#define NTOT (2 * NX + 2 * NW)
#define WS_NEED ((size_t)NTOT * 2)

#define BM 128
#define BN 64
#define BK 32
#define NITER (KDIM / BK)        // 16
#define BUF_B 40960              // X 8KB + H 8KB + 6 x 4KB weights
#define NBUF 4                   // 4-deep circular: 160KB LDS

typedef __attribute__((ext_vector_type(8))) short short8;
typedef __attribute__((ext_vector_type(4))) float floatx4;
typedef __attribute__((ext_vector_type(16))) float floatx16;

__device__ __forceinline__ unsigned int pk2bf(float a, float b) {
    float2 f2; f2.x = a; f2.y = b;
    union { __hip_bfloat162 h; unsigned int u; } cv;
    cv.h = __float22bfloat162_rn(f2);
    return cv.u;
}

__device__ __forceinline__ void async16(const void* g, void* l) {
    __builtin_amdgcn_global_load_lds(
        (const __attribute__((address_space(1))) void*)g,
        (__attribute__((address_space(3))) void*)l, 16, 0, 0);
}

// ---------------- K1: fp32 -> bf16 prepass ----------------
__global__ __launch_bounds__(256)
void convert_bf16_kernel(const float* __restrict__ x, const float* __restrict__ h,
                         const float* __restrict__ wih, const float* __restrict__ whh,
                         unsigned short* __restrict__ ws)
{
    const size_t base = ((size_t)blockIdx.x * 256 + threadIdx.x) * 8;
    const float* src; size_t off;
    if (base < (size_t)OFF_H)        { src = x;   off = OFF_X; }
    else if (base < (size_t)OFF_WIH) { src = h;   off = OFF_H; }
    else if (base < (size_t)OFF_WHH) { src = wih; off = OFF_WIH; }
    else                             { src = whh; off = OFF_WHH; }
    const float4 v0 = *(const float4*)(src + (base - off));
    const float4 v1 = *(const float4*)(src + (base - off) + 4);
    uint4 o;
    o.x = pk2bf(v0.x, v0.y);
    o.y = pk2bf(v0.z, v0.w);
    o.z = pk2bf(v1.x, v1.y);
    o.w = pk2bf(v1.z, v1.w);
    *(uint4*)(ws + base) = o;
}

// ---------------- K2: fused bf16 GEMM + GRU gates (32x32x16 MFMA) ----------------
// Buffer (40KB): X slab [0,8K) 128r x 32k; H [8K,16K); W slab w at 16K+w*4K,
// 64r x 32k. Rows are 64B (32 bf16); 128B "line" = 2 rows = 8 x 16B slots.
// Physical slot p of line L holds logical slot p ^ (L&7),
// logical slot = (row&1)*4 + kchunk(16B).
__global__ __launch_bounds__(512, 2)
void gru_main_kernel(const unsigned short* __restrict__ ws,
                     const float* __restrict__ hidden,
                     const float* __restrict__ b_ih,
                     const float* __restrict__ b_hh,
                     float* __restrict__ out)
{
    const int u  = blockIdx.x >> 3;   // x%8 = nb -> XCD-local weights
    const int nb = blockIdx.x & 7;
    const int mb = blockIdx.y;        // 0..7
    const int b0 = mb * BM;
    const int h0 = nb * BN;

    const int tid  = threadIdx.x;
    const int lane = tid & 63;
    const int wave = tid >> 6;        // 0..7
    const int l5   = lane & 31;       // fragment row (m or n)
    const int kh8  = lane >> 5;       // which 8-k subchunk within a k-half
    const int p    = wave & 3;        // quadrant within gate-group
    const int wm   = p & 1;           // 64-row half of BM=128
    const int wn   = p >> 1;          // 32-col half of BN=64
    const int g2   = wave >> 2;       // 0: gx, 1: gh

    __shared__ __align__(16) char smem[NBUF * BUF_B];   // 160KB

    // ---- staging: 40 x 1KB instrs per buffer, 5 per wave ----
    const unsigned short* baseX = ws + OFF_X + ((size_t)b0 * U_ + u) * I_;
    const unsigned short* baseH = ws + OFF_H + ((size_t)b0 * U_ + u) * H_;
    const unsigned short* wb[6];
    #pragma unroll
    for (int w = 0; w < 3; ++w) {
        wb[w]     = ws + OFF_WIH + ((size_t)(u * 3 + w) * H_ + h0) * I_;
        wb[w + 3] = ws + OFF_WHH + ((size_t)(u * 3 + w) * H_ + h0) * H_;
    }

    const unsigned short* gptr[5];
    int ldsoff[5];
    #pragma unroll
    for (int i = 0; i < 5; ++i) {
        const int j = wave * 5 + i;
        const unsigned short* sbase; int rstr, group, soff;
        if (j < 8)       { sbase = baseX; rstr = U_ * I_; group = j;     soff = 0; }
        else if (j < 16) { sbase = baseH; rstr = U_ * H_; group = j - 8; soff = 8192; }
        else             { const int w = (j - 16) >> 2;
                           sbase = wb[w]; rstr = I_; group = (j - 16) & 3;
                           soff = 16384 + w * 4096; }
        const int line = group * 8 + (lane >> 3);
        const int pos  = (lane & 7) ^ (line & 7);   // logical slot staged by this lane
        const int row  = 2 * line + (pos >> 2);
        const int ch   = pos & 3;
        gptr[i]   = sbase + (size_t)row * rstr + ch * 8;
        ldsoff[i] = soff + group * 1024 + lane * 16;
    }

    // ---- fragment read offsets (within-slab bytes) ----
    // A (m-tile mt, k-half kh): r = wm*64 + mt*32 + l5, chunk c = kh*2 + kh8
    int aoff[2][2], boff[2];
    #pragma unroll
    for (int mt = 0; mt < 2; ++mt)
        #pragma unroll
        for (int kh = 0; kh < 2; ++kh) {
            const int r = wm * 64 + mt * 32 + l5;
            const int c = kh * 2 + kh8;
            const int line = r >> 1;
            const int pp = (((r & 1) * 4 + c)) ^ (line & 7);
            aoff[mt][kh] = line * 128 + pp * 16;
        }
    #pragma unroll
    for (int kh = 0; kh < 2; ++kh) {
        const int r = wn * 32 + l5;
        const int c = kh * 2 + kh8;
        const int line = r >> 1;
        const int pp = (((r & 1) * 4 + c)) ^ (line & 7);
        boff[kh] = line * 128 + pp * 16;
    }

    floatx16 acc[3][2];
    #pragma unroll
    for (int g = 0; g < 3; ++g)
        #pragma unroll
        for (int mt = 0; mt < 2; ++mt)
            #pragma unroll
            for (int r = 0; r < 16; ++r) acc[g][mt][r] = 0.f;

    // ---- prologue: issue tiles 0,1,2 (15 loads in flight per wave) ----
    #pragma unroll
    for (int t = 0; t < 3; ++t) {
        const int slot = t * BUF_B;
        #pragma unroll
        for (int i = 0; i < 5; ++i) {
            async16(gptr[i], smem + slot + ldsoff[i]);
            gptr[i] += BK;
        }
    }

    for (int it = 0; it < NITER; ++it) {
        // Retire ONLY this tile's 5 loads (in-order per wave); keep up to
        // 2 tiles (10 loads) in flight across the barrier. Tail drains.
        if (it < NITER - 2)
            asm volatile("s_waitcnt vmcnt(10)" ::: "memory");
        else if (it == NITER - 2)
            asm volatile("s_waitcnt vmcnt(5)" ::: "memory");
        else
            asm volatile("s_waitcnt vmcnt(0)" ::: "memory");
        __builtin_amdgcn_s_barrier();
        // fence: no LDS access may move above the barrier (raw s_barrier
        // is not a compiler memory fence; this empty clobber is).
        asm volatile("" ::: "memory");

        const char* base  = smem + (it & 3) * BUF_B;
        const char* abase = base + g2 * 8192;     // X for gx, H for gh
        short8 a[2][2];
        #pragma unroll
        for (int mt = 0; mt < 2; ++mt)
            #pragma unroll
            for (int kh = 0; kh < 2; ++kh)
                a[mt][kh] = *(const short8*)(abase + aoff[mt][kh]);

        // issue tile it+3 into slot (it+3)&3 == (it-1)&3 (readers done:
        // all waves passed this iter's barrier after consuming it-1).
        if (it + 3 < NITER) {
            const int slot = ((it + 3) & 3) * BUF_B;
            #pragma unroll
            for (int i = 0; i < 5; ++i) {
                async16(gptr[i], smem + slot + ldsoff[i]);
                gptr[i] += BK;
            }
        }

        __builtin_amdgcn_s_setprio(1);
        #pragma unroll
        for (int g = 0; g < 3; ++g) {
            const char* bslab = base + 16384 + (g2 * 3 + g) * 4096;
            #pragma unroll
            for (int kh = 0; kh < 2; ++kh) {
                const short8 bf = *(const short8*)(bslab + boff[kh]);
                #pragma unroll
                for (int mt = 0; mt < 2; ++mt)
                    acc[g][mt] = __builtin_amdgcn_mfma_f32_32x32x16_bf16(
                        a[mt][kh], bf, acc[g][mt], 0, 0, 0);
            }
        }
        __builtin_amdgcn_s_setprio(0);
    }

    // ---- epilogue: 2 per-mt rounds; lane-matched gh->gx exchange ----
    // C/D 32x32: col = l5, row = (reg&3) + 8*(reg>>2) + 4*kh8.
    // ep layout: float4[(g*4 + p)*64 + lane][qr], qr=0..3 -> 48KB (fits smem).
    float4* ep = (float4*)smem;
    const float* bih = b_ih + u * (3 * H_);
    const float* bhh = b_hh + u * (3 * H_);
    const int col  = h0 + wn * 32 + l5;
    const float bir  = bih[col],          bhr = bhh[col];
    const float biz  = bih[H_ + col],     bhz = bhh[H_ + col];
    const float bin_ = bih[2 * H_ + col], bhn = bhh[2 * H_ + col];

    #pragma unroll
    for (int mt = 0; mt < 2; ++mt) {
        __syncthreads();   // round 0: all K-loop LDS reads done; round 1: ep reuse
        if (g2 == 1) {
            #pragma unroll
            for (int g = 0; g < 3; ++g)
                #pragma unroll
                for (int qr = 0; qr < 4; ++qr)
                    ep[((g * 4 + p) * 64 + lane) * 4 + qr] =
                        (float4){acc[g][mt][qr * 4 + 0], acc[g][mt][qr * 4 + 1],
                                 acc[g][mt][qr * 4 + 2], acc[g][mt][qr * 4 + 3]};
        }
        __syncthreads();
        if (g2 == 0) {
            #pragma unroll
            for (int qr = 0; qr < 4; ++qr) {
                const float4 hrv = ep[((0 * 4 + p) * 64 + lane) * 4 + qr];
                const float4 hzv = ep[((1 * 4 + p) * 64 + lane) * 4 + qr];
                const float4 hnv = ep[((2 * 4 + p) * 64 + lane) * 4 + qr];
                #pragma unroll
                for (int rr = 0; rr < 4; ++rr) {
                    const int reg = qr * 4 + rr;
                    const int row = wm * 64 + mt * 32 + (reg & 3) + 8 * (reg >> 2) + 4 * kh8;
                    const size_t gidx = ((size_t)(b0 + row) * U_ + u) * H_ + col;
                    const float hprev = hidden[gidx];
                    const float hr = (rr == 0 ? hrv.x : rr == 1 ? hrv.y : rr == 2 ? hrv.z : hrv.w) + bhr;
                    const float hz = (rr == 0 ? hzv.x : rr == 1 ? hzv.y : rr == 2 ? hzv.z : hzv.w) + bhz;
                    const float hn = (rr == 0 ? hnv.x : rr == 1 ? hnv.y : rr == 2 ? hnv.z : hnv.w) + bhn;
                    const float xr = acc[0][mt][reg] + bir;
                    const float xz = acc[1][mt][reg] + biz;
                    const float xn = acc[2][mt][reg] + bin_;
                    const float rg = 1.f / (1.f + __expf(-(xr + hr)));
                    const float zg = 1.f / (1.f + __expf(-(xz + hz)));
                    const float ng = tanhf(xn + rg * hn);
                    out[gidx] = (1.f - zg) * ng + zg * hprev;
                }
            }
        }
    }
}

// ---------------- Fallback (proven R3 path): used only if ws too small ----------------
#define LSTR 40
#define ESTR 68
union SmemF {
    short bf[8][64 * LSTR];
    float ep[3][64 * ESTR];
};

__global__ __launch_bounds__(512, 4)
void gru_fallback_kernel(const float* __restrict__ inputs, const float* __restrict__ hidden,
                         const float* __restrict__ W_ih, const float* __restrict__ W_hh,
                         const float* __restrict__ b_ih, const float* __restrict__ b_hh,
                         float* __restrict__ out)
{
    const int nb = blockIdx.x;
    const int mb = blockIdx.y;
    const int u  = blockIdx.z;
    const int b0 = mb * 64, h0 = nb * 64;
    const int tid = threadIdx.x, lane = tid & 63, wave = tid >> 6;
    const int lr = lane & 15, q = lane >> 4;
    const int wm = wave & 1, wn = (wave >> 1) & 1, g2 = wave >> 2;

    __shared__ SmemF smem;

    const float* srcs[8]; int rstr[8];
    srcs[0] = inputs + ((size_t)b0 * U_ + u) * I_;         rstr[0] = U_ * I_;
    srcs[1] = hidden + ((size_t)b0 * U_ + u) * H_;         rstr[1] = U_ * H_;
    srcs[2] = W_ih + ((size_t)(u * 3 + 0) * H_ + h0) * I_; rstr[2] = I_;
    srcs[3] = W_ih + ((size_t)(u * 3 + 1) * H_ + h0) * I_; rstr[3] = I_;
    srcs[4] = W_ih + ((size_t)(u * 3 + 2) * H_ + h0) * I_; rstr[4] = I_;
    srcs[5] = W_hh + ((size_t)(u * 3 + 0) * H_ + h0) * H_; rstr[5] = H_;
    srcs[6] = W_hh + ((size_t)(u * 3 + 1) * H_ + h0) * H_; rstr[6] = H_;
    srcs[7] = W_hh + ((size_t)(u * 3 + 2) * H_ + h0) * H_; rstr[7] = H_;

    const int srow = tid >> 3, c4 = (tid & 7) * 4;
    const float* tb[8];
    #pragma unroll
    for (int s = 0; s < 8; ++s) tb[s] = srcs[s] + (size_t)srow * rstr[s] + c4;

    floatx4 acc[3][2][2];
    #pragma unroll
    for (int g = 0; g < 3; ++g)
        #pragma unroll
        for (int mt = 0; mt < 2; ++mt)
            #pragma unroll
            for (int nt = 0; nt < 2; ++nt) acc[g][mt][nt] = (floatx4){0.f, 0.f, 0.f, 0.f};

    const int aslab = g2, bbase = 2 + 3 * g2;
    float4 pre[8];
    #pragma unroll
    for (int s = 0; s < 8; ++s) pre[s] = *(const float4*)(tb[s]);

    for (int k0 = 0; k0 < KDIM; k0 += 32) {
        #pragma unroll
        for (int s = 0; s < 8; ++s) {
            uint2 w; w.x = pk2bf(pre[s].x, pre[s].y); w.y = pk2bf(pre[s].z, pre[s].w);
            *(uint2*)&smem.bf[s][srow * LSTR + c4] = w;
        }
        __syncthreads();
        if (k0 + 32 < KDIM) {
            #pragma unroll
            for (int s = 0; s < 8; ++s) pre[s] = *(const float4*)(tb[s] + k0 + 32);
        }
        short8 afr[2];
        #pragma unroll
        for (int mt = 0; mt < 2; ++mt)
            afr[mt] = *(const short8*)&smem.bf[aslab][(wm * 32 + mt * 16 + lr) * LSTR + q * 8];
        #pragma unroll
        for (int g = 0; g < 3; ++g) {
            const short8 bf0 = *(const short8*)&smem.bf[bbase + g][(wn * 32 + lr) * LSTR + q * 8];
            const short8 bf1 = *(const short8*)&smem.bf[bbase + g][(wn * 32 + 16 + lr) * LSTR + q * 8];
            #pragma unroll
            for (int mt = 0; mt < 2; ++mt) {
                acc[g][mt][0] = __builtin_amdgcn_mfma_f32_16x16x32_bf16(afr[mt], bf0, acc[g][mt][0], 0, 0, 0);
                acc[g][mt][1] = __builtin_amdgcn_mfma_f32_16x16x32_bf16(afr[mt], bf1, acc[g][mt][1], 0, 0, 0);
            }
        }
        __syncthreads();
    }

    const float* bih = b_ih + u * (3 * H_);
    const float* bhh = b_hh + u * (3 * H_);
    if (g2 == 1) {
        #pragma unroll
        for (int nt = 0; nt < 2; ++nt) {
            const int col = wn * 32 + nt * 16 + lr;
            const float bhr = bhh[h0 + col], bhz = bhh[H_ + h0 + col], bhn = bhh[2 * H_ + h0 + col];
            #pragma unroll
            for (int mt = 0; mt < 2; ++mt)
                #pragma unroll
                for (int r = 0; r < 4; ++r) {
                    const int row = wm * 32 + mt * 16 + q * 4 + r;
                    smem.ep[0][row * ESTR + col] = acc[0][mt][nt][r] + bhr;
                    smem.ep[1][row * ESTR + col] = acc[1][mt][nt][r] + bhz;
                    smem.ep[2][row * ESTR + col] = acc[2][mt][nt][r] + bhn;
                }
        }
    }
    __syncthreads();
    if (g2 == 0) {
        #pragma unroll
        for (int nt = 0; nt < 2; ++nt) {
            const int col = wn * 32 + nt * 16 + lr, hcol = h0 + col;
            const float bir = bih[hcol], biz = bih[H_ + hcol], bin_ = bih[2 * H_ + hcol];
            #pragma unroll
            for (int mt = 0; mt < 2; ++mt)
                #pragma unroll
                for (int r = 0; r < 4; ++r) {
                    const int row = wm * 32 + mt * 16 + q * 4 + r;
                    const size_t gidx = ((size_t)(b0 + row) * U_ + u) * H_ + hcol;
                    const float hprev = hidden[gidx];
                    const float hr = smem.ep[0][row * ESTR + col];
                    const float hz = smem.ep[1][row * ESTR + col];
                    const float hn = smem.ep[2][row * ESTR + col];
                    const float xr = acc[0][mt][nt][r] + bir;
                    const float xz = acc[1][mt][nt][r] + biz;
                    const float xn = acc[2][mt][nt][r] + bin_;
                    const float rg = 1.f / (1.f + __expf(-(xr + hr)));
                    const float zg = 1.f / (1.f + __expf(-(xz + hz)));
                    const float ng = tanhf(xn + rg * hn);
                    out[gidx] = (1.f - zg) * ng + zg * hprev;
                }
        }
    }
}

extern "C" void kernel_launch(void* const* d_in, const int* in_sizes, int n_in,
                              void* d_out, int out_size, void* d_ws, size_t ws_size,
                              hipStream_t stream) {
    const float* inputs = (const float*)d_in[0];
    const float* hidden = (const float*)d_in[1];
    const float* W_ih   = (const float*)d_in[2];
    const float* W_hh   = (const float*)d_in[3];
    const float* b_ih   = (const float*)d_in[4];
    const float* b_hh   = (const float*)d_in[5];
    float* out = (float*)d_out;

    if (ws_size >= WS_NEED) {
        unsigned short* ws = (unsigned short*)d_ws;
        convert_bf16_kernel<<<NTOT / 2048, 256, 0, stream>>>(inputs, hidden, W_ih, W_hh, ws);
        dim3 grid(64, 8, 1);   // x = u*8+nb (x%8 = nb), y = mb (BM=128)
        gru_main_kernel<<<grid, 512, 0, stream>>>(ws, hidden, b_ih, b_hh, out);
    } else {
        dim3 grid(8, 16, 8);
        gru_fallback_kernel<<<grid, 512, 0, stream>>>(inputs, hidden, W_ih, W_hh, b_ih, b_hh, out);
    }
}

// Round 2
// 174.016 us; speedup vs baseline: 1.0119x; 1.0000x over previous
//
#include <hip/hip_runtime.h>
#include <hip/hip_bf16.h>
#include <stdint.h>

// GroupTorchGRU: B=1024, U=8, I=H=512, fp32 in/out.
// R10: K1 prepass (fp32->bf16) + K2 fused GEMM+gates, 4-deep counted-vmcnt
// pipeline with ALL K-loop LDS reads as inline-asm ds_read_b128:
//  - R9 kept the counted s_waitcnt vmcnt(10) but the compiler still saw the
//    short8 LDS loads and (conservatively, vs global_load_lds's LDS writes)
//    inserted its own s_waitcnt vmcnt(0) before them -> every iter drained
//    the just-issued tile (full HBM latency, ~4500cy/iter observed).
//    Volatile asm ds_read on raw 32-bit LDS offsets removes every
//    compiler-visible LDS read from the loop; waits are fully manual:
//    vmcnt(10/5/0) before the barrier, lgkmcnt(4/2/0)+sched_barrier(0)
//    before each gate's MFMA cluster (rule: sched_barrier or MFMA hoists).
//  - Epilogue bank-conflict fix: ep indexed [(slab*4+qr)*64+lane] (lane
//    stride 16B, conflict-free). Old layout was lane-stride 64B = 32-way
//    conflict = the 4.39M SQ_LDS_BANK_CONFLICT (epilogue, not K-loop).
//  - 4 x 40KB circular LDS (160KB, 1 block/CU, 8 waves). Prologue issues
//    tiles 0..2; iter: wait-own-tile, s_barrier, asm a-reads, issue t+3,
//    asm b-reads, counted-lgkm MFMA clusters under s_setprio(1).
//  - vmcnt accounting exact: 5 global_load_lds per wave per tile; epilogue
//    global loads can't hoist past the in-loop "memory" asm.
// Fallback: proven R3 single-kernel path if ws too small.

#define B_ 1024
#define U_ 8
#define I_ 512
#define H_ 512
#define KDIM 512

#define NX (B_ * U_ * I_)
#define NW (U_ * 3 * H_ * I_)
#define OFF_X 0
#define OFF_H NX
#define OFF_WIH (2 * NX)
#define OFF_WHH (2 * NX + NW)
#define NTOT (2 * NX + 2 * NW)
#define WS_NEED ((size_t)NTOT * 2)

#define BM 128
#define BN 64
#define BK 32
#define NITER (KDIM / BK)        // 16
#define BUF_B 40960              // X 8KB + H 8KB + 6 x 4KB weights
#define NBUF 4                   // 4-deep circular: 160KB LDS

typedef __attribute__((ext_vector_type(8))) short short8;
typedef __attribute__((ext_vector_type(4))) float floatx4;
typedef __attribute__((ext_vector_type(16))) float floatx16;

__device__ __forceinline__ unsigned int pk2bf(float a, float b) {
    float2 f2; f2.x = a; f2.y = b;
    union { __hip_bfloat162 h; unsigned int u; } cv;
    cv.h = __float22bfloat162_rn(f2);
    return cv.u;
}

__device__ __forceinline__ void async16(const void* g, void* l) {
    __builtin_amdgcn_global_load_lds(
        (const __attribute__((address_space(1))) void*)g,
        (__attribute__((address_space(3))) void*)l, 16, 0, 0);
}

// Invisible-to-compiler LDS read: raw ds_read_b128 at a 32-bit LDS byte
// offset. No lgkmcnt is implied -- caller must s_waitcnt lgkmcnt(N) +
// sched_barrier(0) before consuming the result.
__device__ __forceinline__ short8 lds_read_b128(unsigned addr) {
    short8 r;
    asm volatile("ds_read_b128 %0, %1" : "=v"(r) : "v"(addr));
    return r;
}

// ---------------- K1: fp32 -> bf16 prepass ----------------
__global__ __launch_bounds__(256)
void convert_bf16_kernel(const float* __restrict__ x, const float* __restrict__ h,
                         const float* __restrict__ wih, const float* __restrict__ whh,
                         unsigned short* __restrict__ ws)
{
    const size_t base = ((size_t)blockIdx.x * 256 + threadIdx.x) * 8;
    const float* src; size_t off;
    if (base < (size_t)OFF_H)        { src = x;   off = OFF_X; }
    else if (base < (size_t)OFF_WIH) { src = h;   off = OFF_H; }
    else if (base < (size_t)OFF_WHH) { src = wih; off = OFF_WIH; }
    else                             { src = whh; off = OFF_WHH; }
    const float4 v0 = *(const float4*)(src + (base - off));
    const float4 v1 = *(const float4*)(src + (base - off) + 4);
    uint4 o;
    o.x = pk2bf(v0.x, v0.y);
    o.y = pk2bf(v0.z, v0.w);
    o.z = pk2bf(v1.x, v1.y);
    o.w = pk2bf(v1.z, v1.w);
    *(uint4*)(ws + base) = o;
}

// ---------------- K2: fused bf16 GEMM + GRU gates (32x32x16 MFMA) ----------------
// Buffer (40KB): X slab [0,8K) 128r x 32k; H [8K,16K); W slab w at 16K+w*4K,
// 64r x 32k. Rows are 64B (32 bf16); 128B "line" = 2 rows = 8 x 16B slots.
// Physical slot p of line L holds logical slot p ^ (L&7),
// logical slot = (row&1)*4 + kchunk(16B).
__global__ __launch_bounds__(512, 2)
void gru_main_kernel(const unsigned short* __restrict__ ws,
                     const float* __restrict__ hidden,
                     const float* __restrict__ b_ih,
                     const float* __restrict__ b_hh,
                     float* __restrict__ out)
{
    const int u  = blockIdx.x >> 3;   // x%8 = nb -> XCD-local weights
    const int nb = blockIdx.x & 7;
    const int mb = blockIdx.y;        // 0..7
    const int b0 = mb * BM;
    const int h0 = nb * BN;

    const int tid  = threadIdx.x;
    const int lane = tid & 63;
    const int wave = tid >> 6;        // 0..7
    const int l5   = lane & 31;       // fragment row (m or n)
    const int kh8  = lane >> 5;       // which 8-k subchunk within a k-half
    const int p    = wave & 3;        // quadrant within gate-group
    const int wm   = p & 1;           // 64-row half of BM=128
    const int wn   = p >> 1;          // 32-col half of BN=64
    const int g2   = wave >> 2;       // 0: gx, 1: gh

    __shared__ __align__(16) char smem[NBUF * BUF_B];   // 160KB

    // ---- staging: 40 x 1KB instrs per buffer, 5 per wave ----
    const unsigned short* baseX = ws + OFF_X + ((size_t)b0 * U_ + u) * I_;
    const unsigned short* baseH = ws + OFF_H + ((size_t)b0 * U_ + u) * H_;
    const unsigned short* wb[6];
    #pragma unroll
    for (int w = 0; w < 3; ++w) {
        wb[w]     = ws + OFF_WIH + ((size_t)(u * 3 + w) * H_ + h0) * I_;
        wb[w + 3] = ws + OFF_WHH + ((size_t)(u * 3 + w) * H_ + h0) * H_;
    }

    const unsigned short* gptr[5];
    int ldsoff[5];
    #pragma unroll
    for (int i = 0; i < 5; ++i) {
        const int j = wave * 5 + i;
        const unsigned short* sbase; int rstr, group, soff;
        if (j < 8)       { sbase = baseX; rstr = U_ * I_; group = j;     soff = 0; }
        else if (j < 16) { sbase = baseH; rstr = U_ * H_; group = j - 8; soff = 8192; }
        else             { const int w = (j - 16) >> 2;
                           sbase = wb[w]; rstr = I_; group = (j - 16) & 3;
                           soff = 16384 + w * 4096; }
        const int line = group * 8 + (lane >> 3);
        const int pos  = (lane & 7) ^ (line & 7);   // logical slot staged by this lane
        const int row  = 2 * line + (pos >> 2);
        const int ch   = pos & 3;
        gptr[i]   = sbase + (size_t)row * rstr + ch * 8;
        ldsoff[i] = soff + group * 1024 + lane * 16;
    }

    // ---- fragment read offsets (within-slab bytes) ----
    // A (m-tile mt, k-half kh): r = wm*64 + mt*32 + l5, chunk c = kh*2 + kh8
    int aoff[2][2], boff[2];
    #pragma unroll
    for (int mt = 0; mt < 2; ++mt)
        #pragma unroll
        for (int kh = 0; kh < 2; ++kh) {
            const int r = wm * 64 + mt * 32 + l5;
            const int c = kh * 2 + kh8;
            const int line = r >> 1;
            const int pp = (((r & 1) * 4 + c)) ^ (line & 7);
            aoff[mt][kh] = line * 128 + pp * 16;
        }
    #pragma unroll
    for (int kh = 0; kh < 2; ++kh) {
        const int r = wn * 32 + l5;
        const int c = kh * 2 + kh8;
        const int line = r >> 1;
        const int pp = (((r & 1) * 4 + c)) ^ (line & 7);
        boff[kh] = line * 128 + pp * 16;
    }

    // 32-bit LDS base offset of smem (generic LDS ptr: low 32b = LDS offset).
    const unsigned sbase_u = (unsigned)(size_t)(void*)smem;
    const unsigned abase_u = sbase_u + (unsigned)(g2 * 8192);
    const unsigned wbase_u = sbase_u + 16384u + (unsigned)(g2 * 3) * 4096u;

    floatx16 acc[3][2];
    #pragma unroll
    for (int g = 0; g < 3; ++g)
        #pragma unroll
        for (int mt = 0; mt < 2; ++mt)
            #pragma unroll
            for (int r = 0; r < 16; ++r) acc[g][mt][r] = 0.f;

    // ---- prologue: issue tiles 0,1,2 (15 loads in flight per wave) ----
    #pragma unroll
    for (int t = 0; t < 3; ++t) {
        const int slot = t * BUF_B;
        #pragma unroll
        for (int i = 0; i < 5; ++i) {
            async16(gptr[i], smem + slot + ldsoff[i]);
            gptr[i] += BK;
        }
    }

    for (int it = 0; it < NITER; ++it) {
        // Retire ONLY this tile's 5 loads (in-order per wave); keep up to
        // 2 tiles (10 loads) in flight across the barrier. Tail drains.
        if (it < NITER - 2)
            asm volatile("s_waitcnt vmcnt(10)" ::: "memory");
        else if (it == NITER - 2)
            asm volatile("s_waitcnt vmcnt(5)" ::: "memory");
        else
            asm volatile("s_waitcnt vmcnt(0)" ::: "memory");
        __builtin_amdgcn_s_barrier();
        asm volatile("" ::: "memory");   // compiler fence around raw barrier

        const unsigned bufo = (unsigned)((it & 3) * BUF_B);

        // a-frags: 4 asm ds_read_b128 (no implied wait)
        short8 a[2][2];
        #pragma unroll
        for (int mt = 0; mt < 2; ++mt)
            #pragma unroll
            for (int kh = 0; kh < 2; ++kh)
                a[mt][kh] = lds_read_b128(abase_u + bufo + (unsigned)aoff[mt][kh]);

        // issue tile it+3 into slot (it+3)&3 == (it-1)&3 (readers passed
        // this iter's barrier after consuming it-1 with lgkmcnt drained).
        if (it + 3 < NITER) {
            const int slot = ((it + 3) & 3) * BUF_B;
            #pragma unroll
            for (int i = 0; i < 5; ++i) {
                async16(gptr[i], smem + slot + ldsoff[i]);
                gptr[i] += BK;
            }
        }

        // b-frags: 6 asm ds_read_b128, issue order b[0][0],b[0][1],...,b[2][1]
        short8 b[3][2];
        #pragma unroll
        for (int g = 0; g < 3; ++g)
            #pragma unroll
            for (int kh = 0; kh < 2; ++kh)
                b[g][kh] = lds_read_b128(wbase_u + bufo + (unsigned)(g * 4096) + (unsigned)boff[kh]);

        // MFMA clusters with counted lgkm waits (10 ds ops issued; DS
        // retires in order): lgkmcnt(4) -> a*,b0* done; (2) -> b1*; (0) -> b2*.
        __builtin_amdgcn_s_setprio(1);
        asm volatile("s_waitcnt lgkmcnt(4)" ::: "memory");
        __builtin_amdgcn_sched_barrier(0);
        #pragma unroll
        for (int kh = 0; kh < 2; ++kh)
            #pragma unroll
            for (int mt = 0; mt < 2; ++mt)
                acc[0][mt] = __builtin_amdgcn_mfma_f32_32x32x16_bf16(
                    a[mt][kh], b[0][kh], acc[0][mt], 0, 0, 0);
        asm volatile("s_waitcnt lgkmcnt(2)" ::: "memory");
        __builtin_amdgcn_sched_barrier(0);
        #pragma unroll
        for (int kh = 0; kh < 2; ++kh)
            #pragma unroll
            for (int mt = 0; mt < 2; ++mt)
                acc[1][mt] = __builtin_amdgcn_mfma_f32_32x32x16_bf16(
                    a[mt][kh], b[1][kh], acc[1][mt], 0, 0, 0);
        asm volatile("s_waitcnt lgkmcnt(0)" ::: "memory");
        __builtin_amdgcn_sched_barrier(0);
        #pragma unroll
        for (int kh = 0; kh < 2; ++kh)
            #pragma unroll
            for (int mt = 0; mt < 2; ++mt)
                acc[2][mt] = __builtin_amdgcn_mfma_f32_32x32x16_bf16(
                    a[mt][kh], b[2][kh], acc[2][mt], 0, 0, 0);
        __builtin_amdgcn_s_setprio(0);
    }

    // ---- epilogue: 2 per-mt rounds; lane-matched gh->gx exchange ----
    // C/D 32x32: col = l5, row = (reg&3) + 8*(reg>>2) + 4*kh8.
    // ep layout: float4[(slab*4 + qr)*64 + lane], slab = g*4+p -> 48KB.
    // Lane stride 16B => linear, conflict-free (old layout was 64B stride
    // = 32-way conflict = the 4.39M SQ_LDS_BANK_CONFLICT).
    float4* ep = (float4*)smem;
    const float* bih = b_ih + u * (3 * H_);
    const float* bhh = b_hh + u * (3 * H_);
    const int col  = h0 + wn * 32 + l5;
    const float bir  = bih[col],          bhr = bhh[col];
    const float biz  = bih[H_ + col],     bhz = bhh[H_ + col];
    const float bin_ = bih[2 * H_ + col], bhn = bhh[2 * H_ + col];

    #pragma unroll
    for (int mt = 0; mt < 2; ++mt) {
        __syncthreads();   // round 0: all K-loop LDS reads done; round 1: ep reuse
        if (g2 == 1) {
            #pragma unroll
            for (int g = 0; g < 3; ++g)
                #pragma unroll
                for (int qr = 0; qr < 4; ++qr)
                    ep[(((g * 4 + p) * 4 + qr) * 64) + lane] =
                        (float4){acc[g][mt][qr * 4 + 0], acc[g][mt][qr * 4 + 1],
                                 acc[g][mt][qr * 4 + 2], acc[g][mt][qr * 4 + 3]};
        }
        __syncthreads();
        if (g2 == 0) {
            #pragma unroll
            for (int qr = 0; qr < 4; ++qr) {
                const float4 hrv = ep[(((0 * 4 + p) * 4 + qr) * 64) + lane];
                const float4 hzv = ep[(((1 * 4 + p) * 4 + qr) * 64) + lane];
                const float4 hnv = ep[(((2 * 4 + p) * 4 + qr) * 64) + lane];
                #pragma unroll
                for (int rr = 0; rr < 4; ++rr) {
                    const int reg = qr * 4 + rr;
                    const int row = wm * 64 + mt * 32 + (reg & 3) + 8 * (reg >> 2) + 4 * kh8;
                    const size_t gidx = ((size_t)(b0 + row) * U_ + u) * H_ + col;
                    const float hprev = hidden[gidx];
                    const float hr = (rr == 0 ? hrv.x : rr == 1 ? hrv.y : rr == 2 ? hrv.z : hrv.w) + bhr;
                    const float hz = (rr == 0 ? hzv.x : rr == 1 ? hzv.y : rr == 2 ? hzv.z : hzv.w) + bhz;
                    const float hn = (rr == 0 ? hnv.x : rr == 1 ? hnv.y : rr == 2 ? hnv.z : hnv.w) + bhn;
                    const float xr = acc[0][mt][reg] + bir;
                    const float xz = acc[1][mt][reg] + biz;
                    const float xn = acc[2][mt][reg] + bin_;
                    const float rg = 1.f / (1.f + __expf(-(xr + hr)));
                    const float zg = 1.f / (1.f + __expf(-(xz + hz)));
                    const float ng = tanhf(xn + rg * hn);
                    out[gidx] = (1.f - zg) * ng + zg * hprev;
                }
            }
        }
    }
}

// ---------------- Fallback (proven R3 path): used only if ws too small ----------------
#define LSTR 40
#define ESTR 68
union SmemF {
    short bf[8][64 * LSTR];
    float ep[3][64 * ESTR];
};

__global__ __launch_bounds__(512, 4)
void gru_fallback_kernel(const float* __restrict__ inputs, const float* __restrict__ hidden,
                         const float* __restrict__ W_ih, const float* __restrict__ W_hh,
                         const float* __restrict__ b_ih, const float* __restrict__ b_hh,
                         float* __restrict__ out)
{
    const int nb = blockIdx.x;
    const int mb = blockIdx.y;
    const int u  = blockIdx.z;
    const int b0 = mb * 64, h0 = nb * 64;
    const int tid = threadIdx.x, lane = tid & 63, wave = tid >> 6;
    const int lr = lane & 15, q = lane >> 4;
    const int wm = wave & 1, wn = (wave >> 1) & 1, g2 = wave >> 2;

    __shared__ SmemF smem;

    const float* srcs[8]; int rstr[8];
    srcs[0] = inputs + ((size_t)b0 * U_ + u) * I_;         rstr[0] = U_ * I_;
    srcs[1] = hidden + ((size_t)b0 * U_ + u) * H_;         rstr[1] = U_ * H_;
    srcs[2] = W_ih + ((size_t)(u * 3 + 0) * H_ + h0) * I_; rstr[2] = I_;
    srcs[3] = W_ih + ((size_t)(u * 3 + 1) * H_ + h0) * I_; rstr[3] = I_;
    srcs[4] = W_ih + ((size_t)(u * 3 + 2) * H_ + h0) * I_; rstr[4] = I_;
    srcs[5] = W_hh + ((size_t)(u * 3 + 0) * H_ + h0) * H_; rstr[5] = H_;
    srcs[6] = W_hh + ((size_t)(u * 3 + 1) * H_ + h0) * H_; rstr[6] = H_;
    srcs[7] = W_hh + ((size_t)(u * 3 + 2) * H_ + h0) * H_; rstr[7] = H_;

    const int srow = tid >> 3, c4 = (tid & 7) * 4;
    const float* tb[8];
    #pragma unroll
    for (int s = 0; s < 8; ++s) tb[s] = srcs[s] + (size_t)srow * rstr[s] + c4;

    floatx4 acc[3][2][2];
    #pragma unroll
    for (int g = 0; g < 3; ++g)
        #pragma unroll
        for (int mt = 0; mt < 2; ++mt)
            #pragma unroll
            for (int nt = 0; nt < 2; ++nt) acc[g][mt][nt] = (floatx4){0.f, 0.f, 0.f, 0.f};

    const int aslab = g2, bbase = 2 + 3 * g2;
    float4 pre[8];
    #pragma unroll
    for (int s = 0; s < 8; ++s) pre[s] = *(const float4*)(tb[s]);

    for (int k0 = 0; k0 < KDIM; k0 += 32) {
        #pragma unroll
        for (int s = 0; s < 8; ++s) {
            uint2 w; w.x = pk2bf(pre[s].x, pre[s].y); w.y = pk2bf(pre[s].z, pre[s].w);
            *(uint2*)&smem.bf[s][srow * LSTR + c4] = w;
        }
        __syncthreads();
        if (k0 + 32 < KDIM) {
            #pragma unroll
            for (int s = 0; s < 8; ++s) pre[s] = *(const float4*)(tb[s] + k0 + 32);
        }
        short8 afr[2];
        #pragma unroll
        for (int mt = 0; mt < 2; ++mt)
            afr[mt] = *(const short8*)&smem.bf[aslab][(wm * 32 + mt * 16 + lr) * LSTR + q * 8];
        #pragma unroll
        for (int g = 0; g < 3; ++g) {
            const short8 bf0 = *(const short8*)&smem.bf[bbase + g][(wn * 32 + lr) * LSTR + q * 8];
            const short8 bf1 = *(const short8*)&smem.bf[bbase + g][(wn * 32 + 16 + lr) * LSTR + q * 8];
            #pragma unroll
            for (int mt = 0; mt < 2; ++mt) {
                acc[g][mt][0] = __builtin_amdgcn_mfma_f32_16x16x32_bf16(afr[mt], bf0, acc[g][mt][0], 0, 0, 0);
                acc[g][mt][1] = __builtin_amdgcn_mfma_f32_16x16x32_bf16(afr[mt], bf1, acc[g][mt][1], 0, 0, 0);
            }
        }
        __syncthreads();
    }

    const float* bih = b_ih + u * (3 * H_);
    const float* bhh = b_hh + u * (3 * H_);
    if (g2 == 1) {
        #pragma unroll
        for (int nt = 0; nt < 2; ++nt) {
            const int col = wn * 32 + nt * 16 + lr;
            const float bhr = bhh[h0 + col], bhz = bhh[H_ + h0 + col], bhn = bhh[2 * H_ + h0 + col];
            #pragma unroll
            for (int mt = 0; mt < 2; ++mt)
                #pragma unroll
                for (int r = 0; r < 4; ++r) {
                    const int row = wm * 32 + mt * 16 + q * 4 + r;
                    smem.ep[0][row * ESTR + col] = acc[0][mt][nt][r] + bhr;
                    smem.ep[1][row * ESTR + col] = acc[1][mt][nt][r] + bhz;
                    smem.ep[2][row * ESTR + col] = acc[2][mt][nt][r] + bhn;
                }
        }
    }
    __syncthreads();
    if (g2 == 0) {
        #pragma unroll
        for (int nt = 0; nt < 2; ++nt) {
            const int col = wn * 32 + nt * 16 + lr, hcol = h0 + col;
            const float bir = bih[hcol], biz = bih[H_ + hcol], bin_ = bih[2 * H_ + hcol];
            #pragma unroll
            for (int mt = 0; mt < 2; ++mt)
                #pragma unroll
                for (int r = 0; r < 4; ++r) {
                    const int row = wm * 32 + mt * 16 + q * 4 + r;
                    const size_t gidx = ((size_t)(b0 + row) * U_ + u) * H_ + hcol;
                    const float hprev = hidden[gidx];
                    const float hr = smem.ep[0][row * ESTR + col];
                    const float hz = smem.ep[1][row * ESTR + col];
                    const float hn = smem.ep[2][row * ESTR + col];
                    const float xr = acc[0][mt][nt][r] + bir;
                    const float xz = acc[1][mt][nt][r] + biz;
                    const float xn = acc[2][mt][nt][r] + bin_;
                    const float rg = 1.f / (1.f + __expf(-(xr + hr)));
                    const float zg = 1.f / (1.f + __expf(-(xz + hz)));
                    const float ng = tanhf(xn + rg * hn);
                    out[gidx] = (1.f - zg) * ng + zg * hprev;
                }
        }
    }
}

extern "C" void kernel_launch(void* const* d_in, const int* in_sizes, int n_in,
                              void* d_out, int out_size, void* d_ws, size_t ws_size,
                              hipStream_t stream) {
    const float* inputs = (const float*)d_in[0];
    const float* hidden = (const float*)d_in[1];
    const float* W_ih   = (const float*)d_in[2];
    const float* W_hh   = (const float*)d_in[3];
    const float* b_ih   = (const float*)d_in[4];
    const float* b_hh   = (const float*)d_in[5];
    float* out = (float*)d_out;

    if (ws_size >= WS_NEED) {
        unsigned short* ws = (unsigned short*)d_ws;
        convert_bf16_kernel<<<NTOT / 2048, 256, 0, stream>>>(inputs, hidden, W_ih, W_hh, ws);
        dim3 grid(64, 8, 1);   // x = u*8+nb (x%8 = nb), y = mb (BM=128)
        gru_main_kernel<<<grid, 512, 0, stream>>>(ws, hidden, b_ih, b_hh, out);
    } else {
        dim3 grid(8, 16, 8);
        gru_fallback_kernel<<<grid, 512, 0, stream>>>(inputs, hidden, W_ih, W_hh, b_ih, b_hh, out);
    }
}